// Round 8
// baseline (287.162 us; speedup 1.0000x reference)
//
#include <hip/hip_runtime.h>

#define TPB 256
#define NB 391            // ceil(100000/256) coarse buckets of 256 nodes
#define CH 8192           // edges per k_placeA block

// ---------------- coarse histogram (LDS-privatized) ----------------

__global__ __launch_bounds__(TPB) void k_hist(const int* __restrict__ dst,
                                              unsigned* __restrict__ gcount, int E) {
    __shared__ unsigned c[512];
    int t = threadIdx.x;
    for (int b = t; b < 512; b += TPB) c[b] = 0;
    __syncthreads();
    int stride = gridDim.x * TPB;
    for (int i = blockIdx.x * TPB + t; i < E; i += stride)
        atomicAdd(&c[(unsigned)dst[i] >> 8], 1u);
    __syncthreads();
    for (int b = t; b < NB; b += TPB)
        if (c[b]) atomicAdd(&gcount[b], c[b]);
}

// ---------------- exclusive scan over NB buckets (1 block) ----------------

__global__ __launch_bounds__(512) void k_scan(const unsigned* __restrict__ gcount,
                                              int* __restrict__ cptr,
                                              unsigned* __restrict__ gcur, int E) {
    __shared__ unsigned s[512];
    int t = threadIdx.x;
    unsigned orig = (t < NB) ? gcount[t] : 0u;
    s[t] = orig;
    __syncthreads();
#pragma unroll
    for (int o = 1; o < 512; o <<= 1) {
        unsigned v = (t >= o) ? s[t - o] : 0u;
        __syncthreads();
        s[t] += v;
        __syncthreads();
    }
    if (t < NB) {
        unsigned ex = s[t] - orig;
        cptr[t] = (int)ex;
        gcur[t] = ex;
    }
    if (t == 0) cptr[NB] = E;
}

// ---------------- chunked coarse bucket sort, LDS-staged grouped writes ----
// packs each edge as  src | ((dst & 255) << 20)

__global__ __launch_bounds__(TPB) void k_placeA(const int* __restrict__ src,
                                                const int* __restrict__ dst,
                                                unsigned* __restrict__ gcur,
                                                unsigned* __restrict__ bkt, int E) {
    __shared__ unsigned val[CH];
    __shared__ unsigned short bid[CH];
    __shared__ unsigned cnt[512], loff[512], lcur[512], basev[512];
    __shared__ unsigned tsum[TPB];
    int t = threadIdx.x;
    int c0 = blockIdx.x * CH;
    int n = E - c0; if (n > CH) n = CH;

    for (int b = t; b < 512; b += TPB) { cnt[b] = 0; lcur[b] = 0; }
    __syncthreads();
    for (int i = t; i < n; i += TPB)
        atomicAdd(&cnt[(unsigned)dst[c0 + i] >> 8], 1u);
    __syncthreads();
    for (int b = t; b < NB; b += TPB)
        basev[b] = cnt[b] ? atomicAdd(&gcur[b], cnt[b]) : 0u;
    unsigned a0 = cnt[2 * t], a1 = cnt[2 * t + 1];
    tsum[t] = a0 + a1;
    __syncthreads();
#pragma unroll
    for (int o = 1; o < TPB; o <<= 1) {
        unsigned v = (t >= o) ? tsum[t - o] : 0u;
        __syncthreads();
        tsum[t] += v;
        __syncthreads();
    }
    unsigned ex = tsum[t] - (a0 + a1);
    loff[2 * t] = ex; loff[2 * t + 1] = ex + a0;
    __syncthreads();
    for (int i = t; i < n; i += TPB) {
        unsigned s = (unsigned)src[c0 + i];
        unsigned d = (unsigned)dst[c0 + i];
        unsigned b = d >> 8;
        unsigned r = atomicAdd(&lcur[b], 1u);
        unsigned slot = loff[b] + r;
        val[slot] = s | ((d & 255u) << 20);
        bid[slot] = (unsigned short)b;
    }
    __syncthreads();
    for (int i = t; i < n; i += TPB) {
        unsigned b = bid[i];
        bkt[basev[b] + ((unsigned)i - loff[b])] = val[i];
    }
}

// ---------------- fine sort within bucket -> CSR + dinv + xs4 --------------

__global__ __launch_bounds__(TPB) void k_fineS(const unsigned* __restrict__ bkt,
                                               const int* __restrict__ cptr,
                                               const float* __restrict__ x,
                                               int* __restrict__ row_ptr,
                                               int* __restrict__ ssrc,
                                               float* __restrict__ dinv,
                                               float4* __restrict__ xs4,
                                               int N, int E) {
    __shared__ unsigned cnt[256], sc[256], off[256];
    int t = threadIdx.x, b = blockIdx.x;
    cnt[t] = 0;
    __syncthreads();
    int p0 = cptr[b], p1 = cptr[b + 1];
    for (int i = p0 + t; i < p1; i += TPB)
        atomicAdd(&cnt[bkt[i] >> 20], 1u);
    __syncthreads();
    unsigned c = cnt[t];
    sc[t] = c;
    __syncthreads();
#pragma unroll
    for (int o = 1; o < 256; o <<= 1) {
        unsigned v = (t >= o) ? sc[t - o] : 0u;
        __syncthreads();
        sc[t] += v;
        __syncthreads();
    }
    unsigned ex = sc[t] - c;
    off[t] = ex;
    int node = (b << 8) + t;
    if (node < N) {
        row_ptr[node] = p0 + (int)ex;
        float dv = rsqrtf((float)(c + 1u));   // +1 = self-loop
        dinv[node] = dv;
        float4 xv;
        xv.x = x[node * 3 + 0] * dv;
        xv.y = x[node * 3 + 1] * dv;
        xv.z = x[node * 3 + 2] * dv;
        xv.w = 0.f;
        xs4[node] = xv;
    }
    if (b == NB - 1 && t == 0) row_ptr[N] = E;
    __syncthreads();
    for (int i = p0 + t; i < p1; i += TPB) {
        unsigned u = bkt[i];
        unsigned r = atomicAdd(&off[u >> 20], 1u);
        ssrc[p0 + (int)r] = (int)(u & 0xFFFFFu);
    }
}

// ---------------- fused layer 1 + layer-2 linear (thread-per-node) ---------
// q = dinv*(self + sum nbr xs4);  h1 = relu(q W1 + b1) on the fly;
// g = dinv * (h1 W2) written SLICE-MAJOR: gs[slice][node][8 floats].

__global__ __launch_bounds__(TPB) void k_l1f(const float4* __restrict__ xs4,
                                             const int* __restrict__ row_ptr,
                                             const int* __restrict__ ssrc,
                                             const float* __restrict__ dinv,
                                             const float* __restrict__ W1,
                                             const float* __restrict__ b1,
                                             const float* __restrict__ W2,
                                             float4* __restrict__ gs, int N) {
    int node = blockIdx.x * TPB + threadIdx.x;
    if (node >= N) return;
    int beg = row_ptr[node], end = row_ptr[node + 1];
    float4 q = xs4[node];                       // self-loop
    int j = beg;
    for (; j + 3 < end; j += 4) {
        int s0 = ssrc[j], s1 = ssrc[j+1], s2 = ssrc[j+2], s3 = ssrc[j+3];
        float4 v0 = xs4[s0], v1 = xs4[s1], v2 = xs4[s2], v3 = xs4[s3];
        q.x += (v0.x + v1.x) + (v2.x + v3.x);
        q.y += (v0.y + v1.y) + (v2.y + v3.y);
        q.z += (v0.z + v1.z) + (v2.z + v3.z);
    }
    for (; j < end; ++j) {
        float4 v = xs4[ssrc[j]];
        q.x += v.x; q.y += v.y; q.z += v.z;
    }
    float dv = dinv[node];
    float q0 = q.x * dv, q1 = q.y * dv, q2 = q.z * dv;

    float acc[64];
#pragma unroll
    for (int f = 0; f < 64; ++f) acc[f] = 0.f;
    for (int kb = 0; kb < 16; ++kb) {
        int k0 = __builtin_amdgcn_readfirstlane(kb) << 2;
        const float* W1k = W1 + k0;             // W1[c*64 + k0+i]
        const float* b1k = b1 + k0;
        float4 hv;
        hv.x = fmaxf(fmaf(q0, W1k[0], fmaf(q1, W1k[64], fmaf(q2, W1k[128], b1k[0]))), 0.f);
        hv.y = fmaxf(fmaf(q0, W1k[1], fmaf(q1, W1k[65], fmaf(q2, W1k[129], b1k[1]))), 0.f);
        hv.z = fmaxf(fmaf(q0, W1k[2], fmaf(q1, W1k[66], fmaf(q2, W1k[130], b1k[2]))), 0.f);
        hv.w = fmaxf(fmaf(q0, W1k[3], fmaf(q1, W1k[67], fmaf(q2, W1k[131], b1k[3]))), 0.f);
        const float* Wr = W2 + (k0 << 6);       // W2[(k0+i)*64 + f]
#pragma unroll
        for (int f = 0; f < 64; ++f) {
            float a = acc[f];
            a = fmaf(hv.x, Wr[f],        a);
            a = fmaf(hv.y, Wr[64  + f],  a);
            a = fmaf(hv.z, Wr[128 + f],  a);
            a = fmaf(hv.w, Wr[192 + f],  a);
            acc[f] = a;
        }
    }
    // slice-major store: gs[(s*N + node)*2 + half]
#pragma unroll
    for (int s = 0; s < 8; ++s) {
        size_t o = ((size_t)(s * N + node)) << 1;
        float4 v0, v1;
        v0.x = acc[8*s+0] * dv; v0.y = acc[8*s+1] * dv;
        v0.z = acc[8*s+2] * dv; v0.w = acc[8*s+3] * dv;
        v1.x = acc[8*s+4] * dv; v1.y = acc[8*s+5] * dv;
        v1.z = acc[8*s+6] * dv; v1.w = acc[8*s+7] * dv;
        gs[o]     = v0;
        gs[o + 1] = v1;
    }
}

// ---------------- feature-sliced layer-2 pull + bias/relu + W3 partials ----
// slice = blockIdx & 7 (XCD-affine); 2 lanes/node (float4 each, 8 floats).
// Each slice's g-region is 3.2 MB -> L2-resident on its XCD.
// partial p_c = dinv * sum_{f in slice} h2_f W3[f][c], atomicAdd into q4.

__global__ __launch_bounds__(TPB) void k_p2s(const float4* __restrict__ gs,
                                             const int* __restrict__ row_ptr,
                                             const int* __restrict__ ssrc,
                                             const float* __restrict__ dinv,
                                             const float* __restrict__ b2,
                                             const float* __restrict__ W3,
                                             float* __restrict__ q4, int N) {
    int slice = blockIdx.x & 7;
    int nb    = blockIdx.x >> 3;
    int t = threadIdx.x;
    int node = nb * 128 + (t >> 1);
    int half = t & 1;
    if (node >= N) return;
    const float4* base = gs + (((size_t)slice * N) << 1) + half;
    int beg = row_ptr[node], end = row_ptr[node + 1];
    float4 a = base[(size_t)node << 1];         // self-loop
    int j = beg;
    for (; j + 3 < end; j += 4) {
        int s0 = ssrc[j], s1 = ssrc[j+1], s2 = ssrc[j+2], s3 = ssrc[j+3];
        float4 v0 = base[(size_t)s0 << 1];
        float4 v1 = base[(size_t)s1 << 1];
        float4 v2 = base[(size_t)s2 << 1];
        float4 v3 = base[(size_t)s3 << 1];
        a.x += (v0.x + v1.x) + (v2.x + v3.x);
        a.y += (v0.y + v1.y) + (v2.y + v3.y);
        a.z += (v0.z + v1.z) + (v2.z + v3.z);
        a.w += (v0.w + v1.w) + (v2.w + v3.w);
    }
    for (; j < end; ++j) {
        float4 v = base[(size_t)ssrc[j] << 1];
        a.x += v.x; a.y += v.y; a.z += v.z; a.w += v.w;
    }
    float dv = dinv[node];
    int f0 = (slice << 3) + (half << 2);        // first of my 4 features
    const float* bb = b2 + f0;
    a.x = fmaxf(fmaf(a.x, dv, bb[0]), 0.f);     // h2 features f0..f0+3
    a.y = fmaxf(fmaf(a.y, dv, bb[1]), 0.f);
    a.z = fmaxf(fmaf(a.z, dv, bb[2]), 0.f);
    a.w = fmaxf(fmaf(a.w, dv, bb[3]), 0.f);
    const float* Wr = W3 + f0 * 3;              // W3[(f0+i)*3 + c]
    float p0 = fmaf(a.x, Wr[0], fmaf(a.y, Wr[3], fmaf(a.z, Wr[6], a.w * Wr[9])));
    float p1 = fmaf(a.x, Wr[1], fmaf(a.y, Wr[4], fmaf(a.z, Wr[7], a.w * Wr[10])));
    float p2 = fmaf(a.x, Wr[2], fmaf(a.y, Wr[5], fmaf(a.z, Wr[8], a.w * Wr[11])));
    p0 += __shfl_xor(p0, 1, 64);                // combine the node's two halves
    p1 += __shfl_xor(p1, 1, 64);
    p2 += __shfl_xor(p2, 1, 64);
    if (half == 0) {
        atomicAdd(&q4[((size_t)node << 2) + 0], p0 * dv);
        atomicAdd(&q4[((size_t)node << 2) + 1], p1 * dv);
        atomicAdd(&q4[((size_t)node << 2) + 2], p2 * dv);
    }
}

// ---------------- layer-3 pull with output epilogue ----------------

__global__ __launch_bounds__(TPB) void k_pull3o(const float* __restrict__ g34,
                                                const int* __restrict__ row_ptr,
                                                const int* __restrict__ ssrc,
                                                const float* __restrict__ dinv,
                                                const float* __restrict__ b3,
                                                float* __restrict__ out, int N) {
    int tid = blockIdx.x * TPB + threadIdx.x;
    int node = tid >> 2, c = tid & 3;
    if (node >= N) return;
    int beg = row_ptr[node], end = row_ptr[node + 1];
    float acc = g34[tid];                       // self-loop
    int j = beg;
    for (; j + 3 < end; j += 4) {
        int s0 = ssrc[j], s1 = ssrc[j+1], s2 = ssrc[j+2], s3 = ssrc[j+3];
        acc += (g34[(s0 << 2) + c] + g34[(s1 << 2) + c])
             + (g34[(s2 << 2) + c] + g34[(s3 << 2) + c]);
    }
    for (; j < end; ++j) acc += g34[(ssrc[j] << 2) + c];
    if (c < 3) out[(size_t)node * 3 + c] = dinv[node] * acc + b3[c];
}

extern "C" void kernel_launch(void* const* d_in, const int* in_sizes, int n_in,
                              void* d_out, int out_size, void* d_ws, size_t ws_size,
                              hipStream_t stream) {
    const float* x  = (const float*)d_in[0];
    const int*   ei = (const int*)  d_in[1];
    const float* W1 = (const float*)d_in[2];
    const float* b1 = (const float*)d_in[3];
    const float* W2 = (const float*)d_in[4];
    const float* b2 = (const float*)d_in[5];
    const float* W3 = (const float*)d_in[6];
    const float* b3 = (const float*)d_in[7];
    float* out = (float*)d_out;

    const int N = in_sizes[0] / 3;       // 100000
    const int E = in_sizes[1] / 2;       // 1600000
    const int* srcI = ei;
    const int* dstI = ei + E;

    // workspace layout (4-byte units); bkt aliases g (bkt dead before g written)
    float*    ws      = (float*)d_ws;
    unsigned* gcount  = (unsigned*)ws;                      // @0      [512]
    int*      cptr    = (int*)     (ws + 512);              // @512    [512]
    unsigned* gcur    = (unsigned*)(ws + 1024);             // @1024   [512]
    int*      row_ptr = (int*)     (ws + 1536);             // [N+4]
    float*    dinv    = ws + 1536 + (N + 4);                // [N]
    int*      ssrc    = (int*)     (dinv + N);              // [E]
    float*    xs4     = (float*)(ssrc + E);                 // [4N]
    float*    q4      = xs4 + (size_t)N * 4;                // [4N]  (g34)
    float*    g       = q4  + (size_t)N * 4;                // [64N] slice-major
    unsigned* bkt     = (unsigned*)g;                       // [E] alias

    hipMemsetAsync(gcount, 0, 512 * sizeof(unsigned), stream);
    hipMemsetAsync(q4, 0, (size_t)N * 4 * sizeof(float), stream);

    int gPlace = (E + CH - 1) / CH;                         // 196
    int gS3    = (N * 4 + TPB - 1) / TPB;                   // 1563
    int gN     = (N + TPB - 1) / TPB;                       // 391
    int gP2s   = 8 * ((N + 127) / 128);                     // 6256

    // graph preprocessing: two-phase counting sort -> CSR + dinv + xs4
    k_hist  <<<384,    TPB, 0, stream>>>(dstI, gcount, E);
    k_scan  <<<1,      512, 0, stream>>>(gcount, cptr, gcur, E);
    k_placeA<<<gPlace, TPB, 0, stream>>>(srcI, dstI, gcur, bkt, E);
    k_fineS <<<NB,     TPB, 0, stream>>>(bkt, cptr, x, row_ptr, ssrc, dinv,
                                         (float4*)xs4, N, E);

    // layer 1 + layer-2 linear fused; g written slice-major
    k_l1f<<<gN, TPB, 0, stream>>>((const float4*)xs4, row_ptr, ssrc, dinv,
                                  W1, b1, W2, (float4*)g, N);

    // layer-2 pull (feature-sliced, XCD-affine) + bias/relu + W3 partials
    k_p2s<<<gP2s, TPB, 0, stream>>>((const float4*)g, row_ptr, ssrc, dinv,
                                    b2, W3, q4, N);

    // layer-3 pull (+bias fused)
    k_pull3o<<<gS3, TPB, 0, stream>>>(q4, row_ptr, ssrc, dinv, b3, out, N);
}

// Round 9
// 226.660 us; speedup vs baseline: 1.2669x; 1.2669x over previous
//
#include <hip/hip_runtime.h>

#define TPB 256
#define NB 391            // ceil(100000/256) coarse buckets of 256 nodes
#define CH 8192           // edges per k_placeA block
#define BS 4736           // fixed bucket stride (mean 4096 + 10 sigma)

// ---- bf16 helpers (manual RNE pack, shift unpack) ----

__device__ __forceinline__ unsigned bpack(float a, float b) {
    unsigned ua = __float_as_uint(a), ub = __float_as_uint(b);
    ua = (ua + 0x7fffu + ((ua >> 16) & 1u)) >> 16;
    ub = (ub + 0x7fffu + ((ub >> 16) & 1u)) >> 16;
    return ua | (ub << 16);
}
__device__ __forceinline__ float blo(unsigned u) { return __uint_as_float(u << 16); }
__device__ __forceinline__ float bhi(unsigned u) { return __uint_as_float(u & 0xffff0000u); }

// ---------------- init fixed bucket cursors ----------------

__global__ __launch_bounds__(512) void k_init(unsigned* __restrict__ gcur) {
    int t = threadIdx.x;
    if (t < NB) gcur[t] = (unsigned)(t * BS);
}

// ---------------- chunked coarse bucket sort, LDS-staged grouped writes ----
// packs each edge as  src | ((dst & 255) << 20)

__global__ __launch_bounds__(TPB) void k_placeA(const int* __restrict__ src,
                                                const int* __restrict__ dst,
                                                unsigned* __restrict__ gcur,
                                                unsigned* __restrict__ bkt, int E) {
    __shared__ unsigned val[CH];
    __shared__ unsigned short bid[CH];
    __shared__ unsigned cnt[512], loff[512], lcur[512], basev[512];
    __shared__ unsigned tsum[TPB];
    int t = threadIdx.x;
    int c0 = blockIdx.x * CH;
    int n = E - c0; if (n > CH) n = CH;

    for (int b = t; b < 512; b += TPB) { cnt[b] = 0; lcur[b] = 0; }
    __syncthreads();
    for (int i = t; i < n; i += TPB)
        atomicAdd(&cnt[(unsigned)dst[c0 + i] >> 8], 1u);
    __syncthreads();
    for (int b = t; b < NB; b += TPB)
        basev[b] = cnt[b] ? atomicAdd(&gcur[b], cnt[b]) : 0u;
    unsigned a0 = cnt[2 * t], a1 = cnt[2 * t + 1];
    tsum[t] = a0 + a1;
    __syncthreads();
#pragma unroll
    for (int o = 1; o < TPB; o <<= 1) {
        unsigned v = (t >= o) ? tsum[t - o] : 0u;
        __syncthreads();
        tsum[t] += v;
        __syncthreads();
    }
    unsigned ex = tsum[t] - (a0 + a1);
    loff[2 * t] = ex; loff[2 * t + 1] = ex + a0;
    __syncthreads();
    for (int i = t; i < n; i += TPB) {
        unsigned s = (unsigned)src[c0 + i];
        unsigned d = (unsigned)dst[c0 + i];
        unsigned b = d >> 8;
        unsigned r = atomicAdd(&lcur[b], 1u);
        unsigned slot = loff[b] + r;
        val[slot] = s | ((d & 255u) << 20);
        bid[slot] = (unsigned short)b;
    }
    __syncthreads();
    for (int i = t; i < n; i += TPB) {
        unsigned b = bid[i];
        bkt[basev[b] + ((unsigned)i - loff[b])] = val[i];
    }
}

// ---------------- fine sort within bucket -> rp2 + dinv + xs4 --------------

__global__ __launch_bounds__(TPB) void k_fineS(const unsigned* __restrict__ bkt,
                                               const unsigned* __restrict__ gcur,
                                               const float* __restrict__ x,
                                               int2* __restrict__ rp2,
                                               int* __restrict__ ssrc,
                                               float* __restrict__ dinv,
                                               float4* __restrict__ xs4, int N) {
    __shared__ unsigned cnt[256], sc[256], off[256];
    int t = threadIdx.x, b = blockIdx.x;
    cnt[t] = 0;
    __syncthreads();
    int p0 = b * BS, p1 = (int)gcur[b];
    for (int i = p0 + t; i < p1; i += TPB)
        atomicAdd(&cnt[bkt[i] >> 20], 1u);
    __syncthreads();
    unsigned c = cnt[t];
    sc[t] = c;
    __syncthreads();
#pragma unroll
    for (int o = 1; o < 256; o <<= 1) {
        unsigned v = (t >= o) ? sc[t - o] : 0u;
        __syncthreads();
        sc[t] += v;
        __syncthreads();
    }
    unsigned ex = sc[t] - c;
    off[t] = (unsigned)p0 + ex;
    int node = (b << 8) + t;
    if (node < N) {
        int beg = p0 + (int)ex;
        rp2[node] = make_int2(beg, beg + (int)c);
        float dv = rsqrtf((float)(c + 1u));   // +1 = self-loop
        dinv[node] = dv;
        float4 xv;
        xv.x = x[node * 3 + 0] * dv;
        xv.y = x[node * 3 + 1] * dv;
        xv.z = x[node * 3 + 2] * dv;
        xv.w = 0.f;
        xs4[node] = xv;
    }
    __syncthreads();
    for (int i = p0 + t; i < p1; i += TPB) {
        unsigned u = bkt[i];
        unsigned r = atomicAdd(&off[u >> 20], 1u);
        ssrc[r] = (int)(u & 0xFFFFFu);
    }
}

// ---------------- fused layer 1 + layer-2 linear (thread-per-node) ---------
// q = dinv*(self + sum nbr xs4);  h1 = relu(q W1 + b1) on the fly;
// g = dinv*(h1 W2) stored BF16 node-major (128 B/node).

__global__ __launch_bounds__(TPB) void k_l1f2(const float4* __restrict__ xs4,
                                              const int2* __restrict__ rp2,
                                              const int* __restrict__ ssrc,
                                              const float* __restrict__ dinv,
                                              const float* __restrict__ W1,
                                              const float* __restrict__ b1,
                                              const float* __restrict__ W2,
                                              uint4* __restrict__ gb, int N) {
    int node = blockIdx.x * TPB + threadIdx.x;
    if (node >= N) return;
    int2 r = rp2[node];
    int beg = r.x, end = r.y;
    float4 q = xs4[node];                       // self-loop
    int j = beg;
    for (; j + 3 < end; j += 4) {
        int s0 = ssrc[j], s1 = ssrc[j+1], s2 = ssrc[j+2], s3 = ssrc[j+3];
        float4 v0 = xs4[s0], v1 = xs4[s1], v2 = xs4[s2], v3 = xs4[s3];
        q.x += (v0.x + v1.x) + (v2.x + v3.x);
        q.y += (v0.y + v1.y) + (v2.y + v3.y);
        q.z += (v0.z + v1.z) + (v2.z + v3.z);
    }
    for (; j < end; ++j) {
        float4 v = xs4[ssrc[j]];
        q.x += v.x; q.y += v.y; q.z += v.z;
    }
    float dv = dinv[node];
    float q0 = q.x * dv, q1 = q.y * dv, q2 = q.z * dv;

    float acc[64];
#pragma unroll
    for (int f = 0; f < 64; ++f) acc[f] = 0.f;
    for (int kb = 0; kb < 16; ++kb) {
        int k0 = __builtin_amdgcn_readfirstlane(kb) << 2;
        const float* W1k = W1 + k0;             // W1[c*64 + k0+i]
        const float* b1k = b1 + k0;
        float4 hv;
        hv.x = fmaxf(fmaf(q0, W1k[0], fmaf(q1, W1k[64], fmaf(q2, W1k[128], b1k[0]))), 0.f);
        hv.y = fmaxf(fmaf(q0, W1k[1], fmaf(q1, W1k[65], fmaf(q2, W1k[129], b1k[1]))), 0.f);
        hv.z = fmaxf(fmaf(q0, W1k[2], fmaf(q1, W1k[66], fmaf(q2, W1k[130], b1k[2]))), 0.f);
        hv.w = fmaxf(fmaf(q0, W1k[3], fmaf(q1, W1k[67], fmaf(q2, W1k[131], b1k[3]))), 0.f);
        const float* Wr = W2 + (k0 << 6);       // W2[(k0+i)*64 + f]
#pragma unroll
        for (int f = 0; f < 64; ++f) {
            float a = acc[f];
            a = fmaf(hv.x, Wr[f],        a);
            a = fmaf(hv.y, Wr[64  + f],  a);
            a = fmaf(hv.z, Wr[128 + f],  a);
            a = fmaf(hv.w, Wr[192 + f],  a);
            acc[f] = a;
        }
    }
#pragma unroll
    for (int g8 = 0; g8 < 8; ++g8) {
        uint4 v;
        v.x = bpack(acc[8*g8+0] * dv, acc[8*g8+1] * dv);
        v.y = bpack(acc[8*g8+2] * dv, acc[8*g8+3] * dv);
        v.z = bpack(acc[8*g8+4] * dv, acc[8*g8+5] * dv);
        v.w = bpack(acc[8*g8+6] * dv, acc[8*g8+7] * dv);
        gb[((size_t)node << 3) + g8] = v;
    }
}

// ---------------- fused layer-2 pull (bf16) + bias/relu + layer-3 linear ---
// 8 lanes/node, 16 B (8 bf16 features) per lane; full in-wave W3 reduction.

__global__ __launch_bounds__(TPB) void k_p2fb(const uint4* __restrict__ gb,
                                              const int2* __restrict__ rp2,
                                              const int* __restrict__ ssrc,
                                              const float* __restrict__ dinv,
                                              const float* __restrict__ b2,
                                              const float* __restrict__ W3,
                                              float* __restrict__ q4, int N) {
    int tid = blockIdx.x * TPB + threadIdx.x;
    int node = tid >> 3, q = tid & 7;
    if (node >= N) return;
    int2 r = rp2[node];
    int beg = r.x, end = r.y;
    float a[8];
    {
        uint4 u = gb[((size_t)node << 3) + q];  // self-loop
        a[0] = blo(u.x); a[1] = bhi(u.x);
        a[2] = blo(u.y); a[3] = bhi(u.y);
        a[4] = blo(u.z); a[5] = bhi(u.z);
        a[6] = blo(u.w); a[7] = bhi(u.w);
    }
    int j = beg;
    for (; j + 3 < end; j += 4) {
        int s0 = ssrc[j], s1 = ssrc[j+1], s2 = ssrc[j+2], s3 = ssrc[j+3];
        uint4 u0 = gb[((size_t)s0 << 3) + q];
        uint4 u1 = gb[((size_t)s1 << 3) + q];
        uint4 u2 = gb[((size_t)s2 << 3) + q];
        uint4 u3 = gb[((size_t)s3 << 3) + q];
        a[0] += (blo(u0.x) + blo(u1.x)) + (blo(u2.x) + blo(u3.x));
        a[1] += (bhi(u0.x) + bhi(u1.x)) + (bhi(u2.x) + bhi(u3.x));
        a[2] += (blo(u0.y) + blo(u1.y)) + (blo(u2.y) + blo(u3.y));
        a[3] += (bhi(u0.y) + bhi(u1.y)) + (bhi(u2.y) + bhi(u3.y));
        a[4] += (blo(u0.z) + blo(u1.z)) + (blo(u2.z) + blo(u3.z));
        a[5] += (bhi(u0.z) + bhi(u1.z)) + (bhi(u2.z) + bhi(u3.z));
        a[6] += (blo(u0.w) + blo(u1.w)) + (blo(u2.w) + blo(u3.w));
        a[7] += (bhi(u0.w) + bhi(u1.w)) + (bhi(u2.w) + bhi(u3.w));
    }
    for (; j < end; ++j) {
        uint4 u = gb[((size_t)ssrc[j] << 3) + q];
        a[0] += blo(u.x); a[1] += bhi(u.x);
        a[2] += blo(u.y); a[3] += bhi(u.y);
        a[4] += blo(u.z); a[5] += bhi(u.z);
        a[6] += blo(u.w); a[7] += bhi(u.w);
    }
    float dv = dinv[node];
    int f0 = q << 3;
    const float* bb = b2 + f0;
    const float* Wr = W3 + f0 * 3;              // W3[(f0+i)*3 + c]
    float p0 = 0.f, p1 = 0.f, p2 = 0.f;
#pragma unroll
    for (int i = 0; i < 8; ++i) {
        float h = fmaxf(fmaf(a[i], dv, bb[i]), 0.f);
        p0 = fmaf(h, Wr[3*i+0], p0);
        p1 = fmaf(h, Wr[3*i+1], p1);
        p2 = fmaf(h, Wr[3*i+2], p2);
    }
#pragma unroll
    for (int off = 1; off < 8; off <<= 1) {     // reduce across the 8-lane group
        p0 += __shfl_xor(p0, off, 64);
        p1 += __shfl_xor(p1, off, 64);
        p2 += __shfl_xor(p2, off, 64);
    }
    if (q < 4) {
        float v = (q == 0) ? p0 * dv : (q == 1) ? p1 * dv : (q == 2) ? p2 * dv : 0.f;
        q4[((size_t)node << 2) + q] = v;
    }
}

// ---------------- layer-3 pull with output epilogue ----------------

__global__ __launch_bounds__(TPB) void k_pull3o(const float* __restrict__ g34,
                                                const int2* __restrict__ rp2,
                                                const int* __restrict__ ssrc,
                                                const float* __restrict__ dinv,
                                                const float* __restrict__ b3,
                                                float* __restrict__ out, int N) {
    int tid = blockIdx.x * TPB + threadIdx.x;
    int node = tid >> 2, c = tid & 3;
    if (node >= N) return;
    int2 r = rp2[node];
    int beg = r.x, end = r.y;
    float acc = g34[tid];                       // self-loop
    int j = beg;
    for (; j + 3 < end; j += 4) {
        int s0 = ssrc[j], s1 = ssrc[j+1], s2 = ssrc[j+2], s3 = ssrc[j+3];
        acc += (g34[(s0 << 2) + c] + g34[(s1 << 2) + c])
             + (g34[(s2 << 2) + c] + g34[(s3 << 2) + c]);
    }
    for (; j < end; ++j) acc += g34[(ssrc[j] << 2) + c];
    if (c < 3) out[(size_t)node * 3 + c] = dinv[node] * acc + b3[c];
}

extern "C" void kernel_launch(void* const* d_in, const int* in_sizes, int n_in,
                              void* d_out, int out_size, void* d_ws, size_t ws_size,
                              hipStream_t stream) {
    const float* x  = (const float*)d_in[0];
    const int*   ei = (const int*)  d_in[1];
    const float* W1 = (const float*)d_in[2];
    const float* b1 = (const float*)d_in[3];
    const float* W2 = (const float*)d_in[4];
    const float* b2 = (const float*)d_in[5];
    const float* W3 = (const float*)d_in[6];
    const float* b3 = (const float*)d_in[7];
    float* out = (float*)d_out;

    const int N = in_sizes[0] / 3;       // 100000
    const int E = in_sizes[1] / 2;       // 1600000
    const int* srcI = ei;
    const int* dstI = ei + E;

    // workspace layout (4-byte units), 16B-aligned segments
    float*    ws   = (float*)d_ws;
    unsigned* gcur = (unsigned*)ws;                         // @0        [512]
    int2*     rp2  = (int2*)    (ws + 512);                 // [N]  (2N u32)
    float*    dinv = ws + 512 + 2 * (size_t)N;              // [N]
    int*      ssrc = (int*)     (dinv + N);                 // [NB*BS]
    float*    xs4  = (float*)(ssrc + (size_t)NB * BS + 4);  // [4N]
    float*    q4   = xs4 + (size_t)N * 4;                   // [4N]
    unsigned* gb   = (unsigned*)(q4 + (size_t)N * 4);       // [32N] bf16 g
    unsigned* bkt  = gb + (size_t)N * 32;                   // [NB*BS]

    int gPlace = (E + CH - 1) / CH;                         // 196
    int gS3    = (N * 4 + TPB - 1) / TPB;                   // 1563
    int gN     = (N + TPB - 1) / TPB;                       // 391
    int gP2    = (int)(((size_t)N * 8 + TPB - 1) / TPB);    // 3125

    // preprocessing: fixed-stride bucket sort -> rp2 + dinv + xs4
    k_init  <<<1,      512, 0, stream>>>(gcur);
    k_placeA<<<gPlace, TPB, 0, stream>>>(srcI, dstI, gcur, bkt, E);
    k_fineS <<<NB,     TPB, 0, stream>>>(bkt, gcur, x, rp2, ssrc, dinv,
                                         (float4*)xs4, N);

    // layer 1 + layer-2 linear fused; g stored bf16 node-major
    k_l1f2<<<gN, TPB, 0, stream>>>((const float4*)xs4, rp2, ssrc, dinv,
                                   W1, b1, W2, (uint4*)gb, N);

    // layer-2 pull (bf16) + bias/relu + layer-3 linear fused
    k_p2fb<<<gP2, TPB, 0, stream>>>((const uint4*)gb, rp2, ssrc, dinv,
                                    b2, W3, q4, N);

    // layer-3 pull (+bias fused)
    k_pull3o<<<gS3, TPB, 0, stream>>>(q4, rp2, ssrc, dinv, b3, out, N);
}

// Round 10
// 211.326 us; speedup vs baseline: 1.3589x; 1.0726x over previous
//
#include <hip/hip_runtime.h>

#define TPB 256
#define NB 391            // ceil(100000/256) coarse buckets of 256 nodes
#define CH 8192           // edges per k_placeA block
#define BS 4736           // fixed bucket stride (mean 4096 + 10 sigma)

// ---- bf16 helpers (manual RNE pack, shift unpack) ----

__device__ __forceinline__ unsigned bpack(float a, float b) {
    unsigned ua = __float_as_uint(a), ub = __float_as_uint(b);
    ua = (ua + 0x7fffu + ((ua >> 16) & 1u)) >> 16;
    ub = (ub + 0x7fffu + ((ub >> 16) & 1u)) >> 16;
    return ua | (ub << 16);
}
__device__ __forceinline__ float blo(unsigned u) { return __uint_as_float(u << 16); }
__device__ __forceinline__ float bhi(unsigned u) { return __uint_as_float(u & 0xffff0000u); }

// ---------------- init fixed bucket cursors ----------------

__global__ __launch_bounds__(512) void k_init(unsigned* __restrict__ gcur) {
    int t = threadIdx.x;
    if (t < NB) gcur[t] = (unsigned)(t * BS);
}

// ---------------- chunked coarse bucket sort, LDS-staged grouped writes ----
// packs each edge as  src | ((dst & 255) << 20)

__global__ __launch_bounds__(TPB) void k_placeA(const int* __restrict__ src,
                                                const int* __restrict__ dst,
                                                unsigned* __restrict__ gcur,
                                                unsigned* __restrict__ bkt, int E) {
    __shared__ unsigned val[CH];
    __shared__ unsigned short bid[CH];
    __shared__ unsigned cnt[512], loff[512], lcur[512], basev[512];
    __shared__ unsigned tsum[TPB];
    int t = threadIdx.x;
    int c0 = blockIdx.x * CH;
    int n = E - c0; if (n > CH) n = CH;

    for (int b = t; b < 512; b += TPB) { cnt[b] = 0; lcur[b] = 0; }
    __syncthreads();
    for (int i = t; i < n; i += TPB)
        atomicAdd(&cnt[(unsigned)dst[c0 + i] >> 8], 1u);
    __syncthreads();
    for (int b = t; b < NB; b += TPB)
        basev[b] = cnt[b] ? atomicAdd(&gcur[b], cnt[b]) : 0u;
    unsigned a0 = cnt[2 * t], a1 = cnt[2 * t + 1];
    tsum[t] = a0 + a1;
    __syncthreads();
#pragma unroll
    for (int o = 1; o < TPB; o <<= 1) {
        unsigned v = (t >= o) ? tsum[t - o] : 0u;
        __syncthreads();
        tsum[t] += v;
        __syncthreads();
    }
    unsigned ex = tsum[t] - (a0 + a1);
    loff[2 * t] = ex; loff[2 * t + 1] = ex + a0;
    __syncthreads();
    for (int i = t; i < n; i += TPB) {
        unsigned s = (unsigned)src[c0 + i];
        unsigned d = (unsigned)dst[c0 + i];
        unsigned b = d >> 8;
        unsigned r = atomicAdd(&lcur[b], 1u);
        unsigned slot = loff[b] + r;
        val[slot] = s | ((d & 255u) << 20);
        bid[slot] = (unsigned short)b;
    }
    __syncthreads();
    for (int i = t; i < n; i += TPB) {
        unsigned b = bid[i];
        bkt[basev[b] + ((unsigned)i - loff[b])] = val[i];
    }
}

// ---------------- fine sort within bucket -> rp2 + dinv + xs4 --------------

__global__ __launch_bounds__(TPB) void k_fineS(const unsigned* __restrict__ bkt,
                                               const unsigned* __restrict__ gcur,
                                               const float* __restrict__ x,
                                               int2* __restrict__ rp2,
                                               int* __restrict__ ssrc,
                                               float* __restrict__ dinv,
                                               float4* __restrict__ xs4, int N) {
    __shared__ unsigned cnt[256], sc[256], off[256];
    int t = threadIdx.x, b = blockIdx.x;
    cnt[t] = 0;
    __syncthreads();
    int p0 = b * BS, p1 = (int)gcur[b];
    for (int i = p0 + t; i < p1; i += TPB)
        atomicAdd(&cnt[bkt[i] >> 20], 1u);
    __syncthreads();
    unsigned c = cnt[t];
    sc[t] = c;
    __syncthreads();
#pragma unroll
    for (int o = 1; o < 256; o <<= 1) {
        unsigned v = (t >= o) ? sc[t - o] : 0u;
        __syncthreads();
        sc[t] += v;
        __syncthreads();
    }
    unsigned ex = sc[t] - c;
    off[t] = (unsigned)p0 + ex;
    int node = (b << 8) + t;
    if (node < N) {
        int beg = p0 + (int)ex;
        rp2[node] = make_int2(beg, beg + (int)c);
        float dv = rsqrtf((float)(c + 1u));   // +1 = self-loop
        dinv[node] = dv;
        float4 xv;
        xv.x = x[node * 3 + 0] * dv;
        xv.y = x[node * 3 + 1] * dv;
        xv.z = x[node * 3 + 2] * dv;
        xv.w = 0.f;
        xs4[node] = xv;
    }
    __syncthreads();
    for (int i = p0 + t; i < p1; i += TPB) {
        unsigned u = bkt[i];
        unsigned r = atomicAdd(&off[u >> 20], 1u);
        ssrc[r] = (int)(u & 0xFFFFFu);
    }
}

// ---------------- fused layer 1 + layer-2 linear (4 lanes/node) ------------
// lane c: aggregates component c of xs4; q broadcast in-group; computes
// h1 = relu(q W1 + b1) on the fly (scalar W1 path); accumulates 16 output
// features from LDS-staged W2; stores bf16 (features c*16..c*16+15).

__global__ __launch_bounds__(TPB) void k_l1q(const float* __restrict__ xs4,
                                             const int2* __restrict__ rp2,
                                             const int* __restrict__ ssrc,
                                             const float* __restrict__ dinv,
                                             const float* __restrict__ W1,
                                             const float* __restrict__ b1,
                                             const float* __restrict__ W2,
                                             uint4* __restrict__ gb, int N) {
    __shared__ float Ws[4096];
    for (int i = threadIdx.x; i < 4096; i += TPB) Ws[i] = W2[i];
    __syncthreads();                            // before any early return!
    int tid = blockIdx.x * TPB + threadIdx.x;
    int node = tid >> 2, c = tid & 3;
    if (node >= N) return;
    int2 r = rp2[node];
    float acc = xs4[tid];                       // xs4[(node<<2)+c], self-loop
    int j = r.x;
    for (; j + 3 < r.y; j += 4) {
        int s0 = ssrc[j], s1 = ssrc[j+1], s2 = ssrc[j+2], s3 = ssrc[j+3];
        acc += (xs4[(s0 << 2) + c] + xs4[(s1 << 2) + c])
             + (xs4[(s2 << 2) + c] + xs4[(s3 << 2) + c]);
    }
    for (; j < r.y; ++j) acc += xs4[(ssrc[j] << 2) + c];
    float dv = dinv[node];
    acc *= dv;
    int base = (threadIdx.x & 63) & ~3;         // my 4-lane group
    float q0 = __shfl(acc, base + 0, 64);
    float q1 = __shfl(acc, base + 1, 64);
    float q2 = __shfl(acc, base + 2, 64);

    float o[16];
#pragma unroll
    for (int i = 0; i < 16; ++i) o[i] = 0.f;
    const int cofs = c << 4;
    for (int kb = 0; kb < 16; ++kb) {
        int k0 = __builtin_amdgcn_readfirstlane(kb) << 2;
        const float* W1k = W1 + k0;             // W1[cc*64 + k0+kk]
        const float* b1k = b1 + k0;
        float h[4];
        h[0] = fmaxf(fmaf(q0, W1k[0], fmaf(q1, W1k[64], fmaf(q2, W1k[128], b1k[0]))), 0.f);
        h[1] = fmaxf(fmaf(q0, W1k[1], fmaf(q1, W1k[65], fmaf(q2, W1k[129], b1k[1]))), 0.f);
        h[2] = fmaxf(fmaf(q0, W1k[2], fmaf(q1, W1k[66], fmaf(q2, W1k[130], b1k[2]))), 0.f);
        h[3] = fmaxf(fmaf(q0, W1k[3], fmaf(q1, W1k[67], fmaf(q2, W1k[131], b1k[3]))), 0.f);
#pragma unroll
        for (int kk = 0; kk < 4; ++kk) {
            const float4* Wp = (const float4*)(Ws + ((k0 + kk) << 6) + cofs);
#pragma unroll
            for (int ii = 0; ii < 4; ++ii) {    // 4 distinct addrs/wave -> broadcast
                float4 w = Wp[ii];
                o[4*ii+0] = fmaf(h[kk], w.x, o[4*ii+0]);
                o[4*ii+1] = fmaf(h[kk], w.y, o[4*ii+1]);
                o[4*ii+2] = fmaf(h[kk], w.z, o[4*ii+2]);
                o[4*ii+3] = fmaf(h[kk], w.w, o[4*ii+3]);
            }
        }
    }
    uint4 v0, v1;
    v0.x = bpack(o[0] * dv,  o[1] * dv);
    v0.y = bpack(o[2] * dv,  o[3] * dv);
    v0.z = bpack(o[4] * dv,  o[5] * dv);
    v0.w = bpack(o[6] * dv,  o[7] * dv);
    v1.x = bpack(o[8] * dv,  o[9] * dv);
    v1.y = bpack(o[10] * dv, o[11] * dv);
    v1.z = bpack(o[12] * dv, o[13] * dv);
    v1.w = bpack(o[14] * dv, o[15] * dv);
    uint4* gp = gb + ((size_t)node << 3) + (c << 1);
    gp[0] = v0;
    gp[1] = v1;
}

// ---------------- fused layer-2 pull (bf16) + bias/relu + layer-3 linear ---
// 8 lanes/node, 16 B (8 bf16 features) per lane; full in-wave W3 reduction.

__global__ __launch_bounds__(TPB) void k_p2fb(const uint4* __restrict__ gb,
                                              const int2* __restrict__ rp2,
                                              const int* __restrict__ ssrc,
                                              const float* __restrict__ dinv,
                                              const float* __restrict__ b2,
                                              const float* __restrict__ W3,
                                              float* __restrict__ q4, int N) {
    int tid = blockIdx.x * TPB + threadIdx.x;
    int node = tid >> 3, q = tid & 7;
    if (node >= N) return;
    int2 r = rp2[node];
    int beg = r.x, end = r.y;
    float a[8];
    {
        uint4 u = gb[((size_t)node << 3) + q];  // self-loop
        a[0] = blo(u.x); a[1] = bhi(u.x);
        a[2] = blo(u.y); a[3] = bhi(u.y);
        a[4] = blo(u.z); a[5] = bhi(u.z);
        a[6] = blo(u.w); a[7] = bhi(u.w);
    }
    int j = beg;
    for (; j + 3 < end; j += 4) {
        int s0 = ssrc[j], s1 = ssrc[j+1], s2 = ssrc[j+2], s3 = ssrc[j+3];
        uint4 u0 = gb[((size_t)s0 << 3) + q];
        uint4 u1 = gb[((size_t)s1 << 3) + q];
        uint4 u2 = gb[((size_t)s2 << 3) + q];
        uint4 u3 = gb[((size_t)s3 << 3) + q];
        a[0] += (blo(u0.x) + blo(u1.x)) + (blo(u2.x) + blo(u3.x));
        a[1] += (bhi(u0.x) + bhi(u1.x)) + (bhi(u2.x) + bhi(u3.x));
        a[2] += (blo(u0.y) + blo(u1.y)) + (blo(u2.y) + blo(u3.y));
        a[3] += (bhi(u0.y) + bhi(u1.y)) + (bhi(u2.y) + bhi(u3.y));
        a[4] += (blo(u0.z) + blo(u1.z)) + (blo(u2.z) + blo(u3.z));
        a[5] += (bhi(u0.z) + bhi(u1.z)) + (bhi(u2.z) + bhi(u3.z));
        a[6] += (blo(u0.w) + blo(u1.w)) + (blo(u2.w) + blo(u3.w));
        a[7] += (bhi(u0.w) + bhi(u1.w)) + (bhi(u2.w) + bhi(u3.w));
    }
    for (; j < end; ++j) {
        uint4 u = gb[((size_t)ssrc[j] << 3) + q];
        a[0] += blo(u.x); a[1] += bhi(u.x);
        a[2] += blo(u.y); a[3] += bhi(u.y);
        a[4] += blo(u.z); a[5] += bhi(u.z);
        a[6] += blo(u.w); a[7] += bhi(u.w);
    }
    float dv = dinv[node];
    int f0 = q << 3;
    const float* bb = b2 + f0;
    const float* Wr = W3 + f0 * 3;              // W3[(f0+i)*3 + c]
    float p0 = 0.f, p1 = 0.f, p2 = 0.f;
#pragma unroll
    for (int i = 0; i < 8; ++i) {
        float h = fmaxf(fmaf(a[i], dv, bb[i]), 0.f);
        p0 = fmaf(h, Wr[3*i+0], p0);
        p1 = fmaf(h, Wr[3*i+1], p1);
        p2 = fmaf(h, Wr[3*i+2], p2);
    }
#pragma unroll
    for (int off = 1; off < 8; off <<= 1) {     // reduce across the 8-lane group
        p0 += __shfl_xor(p0, off, 64);
        p1 += __shfl_xor(p1, off, 64);
        p2 += __shfl_xor(p2, off, 64);
    }
    if (q < 4) {
        float v = (q == 0) ? p0 * dv : (q == 1) ? p1 * dv : (q == 2) ? p2 * dv : 0.f;
        q4[((size_t)node << 2) + q] = v;
    }
}

// ---------------- layer-3 pull with output epilogue ----------------

__global__ __launch_bounds__(TPB) void k_pull3o(const float* __restrict__ g34,
                                                const int2* __restrict__ rp2,
                                                const int* __restrict__ ssrc,
                                                const float* __restrict__ dinv,
                                                const float* __restrict__ b3,
                                                float* __restrict__ out, int N) {
    int tid = blockIdx.x * TPB + threadIdx.x;
    int node = tid >> 2, c = tid & 3;
    if (node >= N) return;
    int2 r = rp2[node];
    int beg = r.x, end = r.y;
    float acc = g34[tid];                       // self-loop
    int j = beg;
    for (; j + 3 < end; j += 4) {
        int s0 = ssrc[j], s1 = ssrc[j+1], s2 = ssrc[j+2], s3 = ssrc[j+3];
        acc += (g34[(s0 << 2) + c] + g34[(s1 << 2) + c])
             + (g34[(s2 << 2) + c] + g34[(s3 << 2) + c]);
    }
    for (; j < end; ++j) acc += g34[(ssrc[j] << 2) + c];
    if (c < 3) out[(size_t)node * 3 + c] = dinv[node] * acc + b3[c];
}

extern "C" void kernel_launch(void* const* d_in, const int* in_sizes, int n_in,
                              void* d_out, int out_size, void* d_ws, size_t ws_size,
                              hipStream_t stream) {
    const float* x  = (const float*)d_in[0];
    const int*   ei = (const int*)  d_in[1];
    const float* W1 = (const float*)d_in[2];
    const float* b1 = (const float*)d_in[3];
    const float* W2 = (const float*)d_in[4];
    const float* b2 = (const float*)d_in[5];
    const float* W3 = (const float*)d_in[6];
    const float* b3 = (const float*)d_in[7];
    float* out = (float*)d_out;

    const int N = in_sizes[0] / 3;       // 100000
    const int E = in_sizes[1] / 2;       // 1600000
    const int* srcI = ei;
    const int* dstI = ei + E;

    // workspace layout (4-byte units), 16B-aligned segments
    float*    ws   = (float*)d_ws;
    unsigned* gcur = (unsigned*)ws;                         // @0        [512]
    int2*     rp2  = (int2*)    (ws + 512);                 // [N]  (2N u32)
    float*    dinv = ws + 512 + 2 * (size_t)N;              // [N]
    int*      ssrc = (int*)     (dinv + N);                 // [NB*BS]
    float*    xs4  = (float*)(ssrc + (size_t)NB * BS + 4);  // [4N]
    float*    q4   = xs4 + (size_t)N * 4;                   // [4N]
    unsigned* gb   = (unsigned*)(q4 + (size_t)N * 4);       // [32N] bf16 g
    unsigned* bkt  = gb + (size_t)N * 32;                   // [NB*BS]

    int gPlace = (E + CH - 1) / CH;                         // 196
    int gS3    = (N * 4 + TPB - 1) / TPB;                   // 1563
    int gP2    = (int)(((size_t)N * 8 + TPB - 1) / TPB);    // 3125

    // preprocessing: fixed-stride bucket sort -> rp2 + dinv + xs4
    k_init  <<<1,      512, 0, stream>>>(gcur);
    k_placeA<<<gPlace, TPB, 0, stream>>>(srcI, dstI, gcur, bkt, E);
    k_fineS <<<NB,     TPB, 0, stream>>>(bkt, gcur, x, rp2, ssrc, dinv,
                                         (float4*)xs4, N);

    // layer 1 + layer-2 linear fused (4 lanes/node); g stored bf16 node-major
    k_l1q<<<gS3, TPB, 0, stream>>>(xs4, rp2, ssrc, dinv,
                                   W1, b1, W2, (uint4*)gb, N);

    // layer-2 pull (bf16) + bias/relu + layer-3 linear fused
    k_p2fb<<<gP2, TPB, 0, stream>>>((const uint4*)gb, rp2, ssrc, dinv,
                                    b2, W3, q4, N);

    // layer-3 pull (+bias fused)
    k_pull3o<<<gS3, TPB, 0, stream>>>(q4, rp2, ssrc, dinv, b3, out, N);
}